// Round 1
// baseline (4621.887 us; speedup 1.0000x reference)
//
#include <hip/hip_runtime.h>
#include <hip/hip_bf16.h>

#define N_NEUR 2000
#define N_E    1600
#define KPAD   2048
#define NCOND  96
#define NSTEP  60
#define NAVG   15

#define DEGF   0.017453292519943295f
#define TWO_DEG 0.03490658503988659f

// ---------------- Ricciardi transfer function ----------------
__device__ __forceinline__ float f_ricci(float x){
    float t = -x / (1.0f + x);
    float p = 0.14805913578876898f;
    p = fmaf(p, t, 0.64290613877355551f);
    p = fmaf(p, t, 1.0616084849547165f);
    p = fmaf(p, t, 0.93524391761244940f);
    p = fmaf(p, t, 0.62718906618071668f);
    p = fmaf(p, t, 0.32171431660633076f);
    p = fmaf(p, t, 0.32056016125642045f);
    p = fmaf(p, t, 0.77373949685442023f);
    p = fmaf(p, t, 0.22757881388024176f);
    return logf(2.0f * x + 1.0f) + p * t;
}

__device__ __forceinline__ float g_ricci(float x){
    float z = x / (2.0f + x);
    float z2 = z * z, z3 = z2 * z, z4 = z2 * z2, z5 = z4 * z, z6 = z3 * z3, z7 = z6 * z, z8 = z4 * z4;
    float en = 3.5441754117462949f * z - 7.0529131065835378f * z2 - 56.532378057580381f * z3
             + 279.56761105465944f * z4 - 520.37554793489681f * z5
             + 456.58245777026514f * z6 - 155.73340457809226f * z7;
    float de = 1.0f - 4.1357968834226053f * z - 7.2984226138266743f * z2
             + 98.656602235468327f * z3 - 334.20436223415163f * z4
             + 601.08633903294185f * z5 - 599.58577549598340f * z6
             + 277.18420330693891f * z7 - 16.445022798669722f * z8;
    return en / de;
}

__device__ __forceinline__ float phi_rate(float mu, float sigma, float tau_ref){
    const float tau = 0.01f;
    float xp = mu / sigma;
    float xm = (mu - 20.0f) / sigma;
    float r;
    if (xm > 0.0f){
        r = 1.0f / (f_ricci(xp) - f_ricci(xm));
    } else if (xp > 0.0f){
        float nxm = fminf(-xm, 9.0f);                    // -xm >= 0 here
        r = 1.0f / (f_ricci(xp) + expf(nxm * nxm) * g_ricci(nxm));
    } else {
        float nxp = fminf(fmaxf(-xp, 0.0f), 9.0f);
        float nxm = fminf(-xm, 9.0f);                    // xm < xp <= 0 -> -xm > 0
        float arg = g_ricci(nxm) - expf(nxp * nxp - nxm * nxm) * g_ricci(nxp);
        r = expf(-nxm * nxm - logf(fmaxf(arg, 1e-12f)));
    }
    return 1.0f / (tau_ref + tau / fmaxf(r, 1e-12f));
}

__device__ __forceinline__ float pref_of(int n){
    return (n < N_E) ? (float)n * (179.99f / 1599.0f)
                     : (float)(n - N_E) * (179.99f / 399.0f);
}

// ---------------- weight build ----------------
__global__ __launch_bounds__(256) void build_w_kernel(
    const float* __restrict__ jp, const float* __restrict__ pp,
    const float* __restrict__ wp, const float* __restrict__ rnd,
    float* __restrict__ W, float* __restrict__ W2)
{
    int e = blockIdx.x * 256 + threadIdx.x;     // over 2000*2048
    int i = e >> 11;
    int j = e & (KPAD - 1);
    if (i >= N_NEUR) return;
    if (j >= N_NEUR){ W[e] = 0.0f; W2[e] = 0.0f; return; }
    int isIi = (i >= N_E) ? 1 : 0;
    int isIj = (j >= N_E) ? 1 : 0;
    int conn = 2 * isIj + isIi;
    float J  = expf(jp[conn]);
    float P  = 1.0f / (1.0f + expf(-2.0f * expf(pp[conn])));
    float Wd = expf(wp[conn]);
    float diff = fabsf(pref_of(i) - pref_of(j));
    float dw = DEGF * Wd;
    float z = expf((cosf(TWO_DEG * diff) - 1.0f) / (4.0f * dw * dw));
    float s = 1.0f / (1.0f + expf(-32.0f * (P * z - rnd[i * N_NEUR + j])));
    float sign = isIj ? -1.0f : 1.0f;
    float w = sign * J * s;
    W[e]  = w;
    W2[e] = w * w;
}

__global__ __launch_bounds__(256) void build_im_kernel(float* __restrict__ IM)
{
    int e = blockIdx.x * 256 + threadIdx.x;     // over 96*2048
    int c = e >> 11;
    int n = e & (KPAD - 1);
    if (n >= N_NEUR){ IM[e] = 0.0f; return; }
    const float contrasts[8] = {0.0f, 0.0432773f, 0.103411f, 0.186966f,
                                0.303066f, 0.464386f, 0.68854f, 1.0f};
    int ci = c / 12;
    int oi = c - ci * 12;
    float orient = (float)oi * 15.0f;
    const float dw = DEGF * 30.0f;
    float g = expf((cosf(TWO_DEG * (orient - pref_of(n))) - 1.0f) / (4.0f * dw * dw));
    IM[e] = contrasts[ci] * 20.0f * g;
}

// ---------------- one Euler step: mu/sig GEMM + Phi + update ----------------
// grid 250 blocks x 512 threads; block owns neurons [i0, i0+8) x all 96 conditions.
__global__ __launch_bounds__(512) void step_kernel(
    const float* __restrict__ W, const float* __restrict__ W2,
    const float* __restrict__ IM, const float* __restrict__ r_in,
    float* __restrict__ r_out, unsigned int* __restrict__ m_step)
{
    __shared__ float smem[12672 + 1056 + 1056];
    float* r_lds  = smem;            // [96][132]
    float* w_lds  = smem + 12672;    // [8][132]
    float* w2_lds = w_lds + 1056;    // [8][132]

    const int t    = threadIdx.x;
    const int wave = t >> 6;
    const int lane = t & 63;
    const int ip   = lane & 3;       // i in {ip, ip+4}
    const int cg   = lane >> 2;      // c in {cg + 16k}
    const int i0   = blockIdx.x * 8;
    const int jb0  = wave * 16;      // this wave's K-slice within each 128-chunk

    float acc1[2][6], acc2[2][6];
    #pragma unroll
    for (int e = 0; e < 2; ++e)
        #pragma unroll
        for (int k = 0; k < 6; ++k){ acc1[e][k] = 0.0f; acc2[e][k] = 0.0f; }

    // async-stage registers (T14): loads for chunk s+1 issued before compute of s
    float4 pr[6]; float4 pw;
    const int wrow  = (t >> 5) & 7;
    const int wcol4 = (t & 31) << 2;
    const float* wsrc = (t < 256) ? W : W2;

    // issue loads for chunk 0
    {
        #pragma unroll
        for (int n = 0; n < 6; ++n){
            int q = t + 512 * n;
            int row = q >> 5, col4 = (q & 31) << 2;
            pr[n] = *reinterpret_cast<const float4*>(&r_in[row * KPAD + col4]);
        }
        pw = *reinterpret_cast<const float4*>(&wsrc[(i0 + wrow) * KPAD + wcol4]);
    }

    for (int s = 0; s < 16; ++s){
        __syncthreads();   // LDS free (previous compute done)
        #pragma unroll
        for (int n = 0; n < 6; ++n){
            int q = t + 512 * n;
            int row = q >> 5, col4 = (q & 31) << 2;
            *reinterpret_cast<float4*>(&r_lds[row * 132 + col4]) = pr[n];
        }
        {
            float* dst = (t < 256) ? w_lds : w2_lds;
            *reinterpret_cast<float4*>(&dst[wrow * 132 + wcol4]) = pw;
        }
        __syncthreads();
        if (s < 15){
            int base = (s + 1) * 128;
            #pragma unroll
            for (int n = 0; n < 6; ++n){
                int q = t + 512 * n;
                int row = q >> 5, col4 = (q & 31) << 2;
                pr[n] = *reinterpret_cast<const float4*>(&r_in[row * KPAD + base + col4]);
            }
            pw = *reinterpret_cast<const float4*>(&wsrc[(i0 + wrow) * KPAD + base + wcol4]);
        }
        #pragma unroll
        for (int g = 0; g < 4; ++g){
            int jb = jb0 + 4 * g;
            const float4 w0 = *reinterpret_cast<const float4*>(&w_lds[ ip      * 132 + jb]);
            const float4 w1 = *reinterpret_cast<const float4*>(&w_lds[(ip + 4) * 132 + jb]);
            const float4 u0 = *reinterpret_cast<const float4*>(&w2_lds[ ip      * 132 + jb]);
            const float4 u1 = *reinterpret_cast<const float4*>(&w2_lds[(ip + 4) * 132 + jb]);
            #pragma unroll
            for (int k = 0; k < 6; ++k){
                const float4 rv = *reinterpret_cast<const float4*>(&r_lds[(cg + 16 * k) * 132 + jb]);
                acc1[0][k] = fmaf(rv.x, w0.x, acc1[0][k]);
                acc1[0][k] = fmaf(rv.y, w0.y, acc1[0][k]);
                acc1[0][k] = fmaf(rv.z, w0.z, acc1[0][k]);
                acc1[0][k] = fmaf(rv.w, w0.w, acc1[0][k]);
                acc2[0][k] = fmaf(rv.x, u0.x, acc2[0][k]);
                acc2[0][k] = fmaf(rv.y, u0.y, acc2[0][k]);
                acc2[0][k] = fmaf(rv.z, u0.z, acc2[0][k]);
                acc2[0][k] = fmaf(rv.w, u0.w, acc2[0][k]);
                acc1[1][k] = fmaf(rv.x, w1.x, acc1[1][k]);
                acc1[1][k] = fmaf(rv.y, w1.y, acc1[1][k]);
                acc1[1][k] = fmaf(rv.z, w1.z, acc1[1][k]);
                acc1[1][k] = fmaf(rv.w, w1.w, acc1[1][k]);
                acc2[1][k] = fmaf(rv.x, u1.x, acc2[1][k]);
                acc2[1][k] = fmaf(rv.y, u1.y, acc2[1][k]);
                acc2[1][k] = fmaf(rv.z, u1.z, acc2[1][k]);
                acc2[1][k] = fmaf(rv.w, u1.w, acc2[1][k]);
            }
        }
    }
    __syncthreads();

    // cross-wave reduction: red[wave][a*768 + il*96 + c] aliased on r_lds
    float* red = smem;
    #pragma unroll
    for (int e = 0; e < 2; ++e)
        #pragma unroll
        for (int k = 0; k < 6; ++k){
            int o = (ip + 4 * e) * 96 + (cg + 16 * k);
            red[wave * 1536 + o]       = acc1[e][k];
            red[wave * 1536 + 768 + o] = acc2[e][k];
        }
    __syncthreads();

    float* vbuf = smem + 12672;  // reuse w_lds area, 768 floats [c][il]
    for (int o = t; o < 768; o += 512){
        float ms_ = 0.0f, ss_ = 0.0f;
        #pragma unroll
        for (int w = 0; w < 8; ++w){
            ms_ += red[w * 1536 + o];
            ss_ += red[w * 1536 + 768 + o];
        }
        int il = o / 96;
        int c  = o - il * 96;
        int i  = i0 + il;
        float mu = fmaf(0.01f, ms_, IM[c * KPAD + i]);
        float sg = sqrtf(fmaf(0.01f, ss_, 25.0f));
        bool isI = (i >= N_E);
        float rate = phi_rate(mu, sg, isI ? 0.001f : 0.005f);
        float rold = r_in[c * KPAD + i];
        float dr = (isI ? 0.2f : 0.1f) * (rate - rold);
        float rnew = rold + dr;
        r_out[c * KPAD + i] = rnew;
        vbuf[c * 8 + il] = fabsf(dr) / fmaxf(fabsf(rnew), 1.0f);
    }
    __syncthreads();
    if (t < NCOND){
        float mx = 0.0f;
        #pragma unroll
        for (int il = 0; il < 8; ++il) mx = fmaxf(mx, vbuf[t * 8 + il]);
        atomicMax(m_step + t, __float_as_uint(mx * 1e5f));
    }
}

// ---------------- outputs ----------------
__global__ __launch_bounds__(256) void transpose_kernel(
    const float* __restrict__ r_fin, float* __restrict__ out)
{
    int e = blockIdx.x * 256 + threadIdx.x;     // over 192000
    int n = e / NCOND;
    int c = e - n * NCOND;
    out[e] = r_fin[c * KPAD + n];               // out[n*96 + c]
}

__global__ __launch_bounds__(256) void finalize_kernel(
    const unsigned int* __restrict__ m_buf, float* __restrict__ out)
{
    __shared__ float sbuf[256];
    float s = 0.0f;
    for (int idx = threadIdx.x; idx < (NAVG * NCOND); idx += 256)
        s += __uint_as_float(m_buf[(NSTEP - NAVG) * NCOND + idx]);
    sbuf[threadIdx.x] = s;
    __syncthreads();
    for (int st = 128; st > 0; st >>= 1){
        if (threadIdx.x < st) sbuf[threadIdx.x] += sbuf[threadIdx.x + st];
        __syncthreads();
    }
    if (threadIdx.x == 0) out[N_NEUR * NCOND] = sbuf[0] / (float)(NAVG * NCOND);
}

extern "C" void kernel_launch(void* const* d_in, const int* in_sizes, int n_in,
                              void* d_out, int out_size, void* d_ws, size_t ws_size,
                              hipStream_t stream) {
    const float* jp  = (const float*)d_in[0];
    const float* pp  = (const float*)d_in[1];
    const float* wp  = (const float*)d_in[2];
    const float* rnd = (const float*)d_in[3];
    float* out = (float*)d_out;

    float* W  = (float*)d_ws;                          // 2000*2048
    float* W2 = W  + (size_t)N_NEUR * KPAD;            // 2000*2048
    float* IM = W2 + (size_t)N_NEUR * KPAD;            // 96*2048
    float* ra = IM + (size_t)NCOND * KPAD;             // 96*2048
    float* rb = ra + (size_t)NCOND * KPAD;             // 96*2048
    float* mb = rb + (size_t)NCOND * KPAD;             // 60*96

    // zero r buffers (pads included, r0 = 0) and the convergence-metric buffer
    hipMemsetAsync(ra, 0, (size_t)(2 * NCOND * KPAD + NSTEP * NCOND) * sizeof(float), stream);

    build_w_kernel<<<(N_NEUR * KPAD) / 256, 256, 0, stream>>>(jp, pp, wp, rnd, W, W2);
    build_im_kernel<<<(NCOND * KPAD) / 256, 256, 0, stream>>>(IM);

    const float* rin = ra;
    float* rout = rb;
    for (int s = 0; s < NSTEP; ++s){
        step_kernel<<<N_NEUR / 8, 512, 0, stream>>>(W, W2, IM, rin, rout,
                                                    (unsigned int*)mb + s * NCOND);
        float* tmp = (float*)rin; rin = rout; rout = tmp;
    }
    // after the loop, `rin` points at the buffer written by the last step
    transpose_kernel<<<(N_NEUR * NCOND) / 256, 256, 0, stream>>>(rin, out);
    finalize_kernel<<<1, 256, 0, stream>>>((const unsigned int*)mb, out);
}

// Round 2
// 2995.758 us; speedup vs baseline: 1.5428x; 1.5428x over previous
//
#include <hip/hip_runtime.h>
#include <hip/hip_bf16.h>

#define N_NEUR 2000
#define N_E    1600
#define KPAD   2048
#define NCOND  96
#define NSTEP  60
#define NAVG   15
#define CHUNK  64
#define NCH    32           // KPAD / CHUNK
#define RSTRIDE 66          // r tile row stride (floats): 2-way banks, 8B aligned
#define WSTRIDE 68          // W tile row stride (floats): 16B aligned, broadcast reads

#define DEGF   0.017453292519943295f
#define TWO_DEG 0.03490658503988659f

// ---------------- Ricciardi transfer function ----------------
__device__ __forceinline__ float f_ricci(float x){
    float t = -x / (1.0f + x);
    float p = 0.14805913578876898f;
    p = fmaf(p, t, 0.64290613877355551f);
    p = fmaf(p, t, 1.0616084849547165f);
    p = fmaf(p, t, 0.93524391761244940f);
    p = fmaf(p, t, 0.62718906618071668f);
    p = fmaf(p, t, 0.32171431660633076f);
    p = fmaf(p, t, 0.32056016125642045f);
    p = fmaf(p, t, 0.77373949685442023f);
    p = fmaf(p, t, 0.22757881388024176f);
    return logf(2.0f * x + 1.0f) + p * t;
}

__device__ __forceinline__ float g_ricci(float x){
    float z = x / (2.0f + x);
    float z2 = z * z, z3 = z2 * z, z4 = z2 * z2, z5 = z4 * z, z6 = z3 * z3, z7 = z6 * z, z8 = z4 * z4;
    float en = 3.5441754117462949f * z - 7.0529131065835378f * z2 - 56.532378057580381f * z3
             + 279.56761105465944f * z4 - 520.37554793489681f * z5
             + 456.58245777026514f * z6 - 155.73340457809226f * z7;
    float de = 1.0f - 4.1357968834226053f * z - 7.2984226138266743f * z2
             + 98.656602235468327f * z3 - 334.20436223415163f * z4
             + 601.08633903294185f * z5 - 599.58577549598340f * z6
             + 277.18420330693891f * z7 - 16.445022798669722f * z8;
    return en / de;
}

__device__ __forceinline__ float phi_rate(float mu, float sigma, float tau_ref){
    const float tau = 0.01f;
    float xp = mu / sigma;
    float xm = (mu - 20.0f) / sigma;
    float r;
    if (xm > 0.0f){
        r = 1.0f / (f_ricci(xp) - f_ricci(xm));
    } else if (xp > 0.0f){
        float nxm = fminf(-xm, 9.0f);
        r = 1.0f / (f_ricci(xp) + expf(nxm * nxm) * g_ricci(nxm));
    } else {
        float nxp = fminf(fmaxf(-xp, 0.0f), 9.0f);
        float nxm = fminf(-xm, 9.0f);
        float arg = g_ricci(nxm) - expf(nxp * nxp - nxm * nxm) * g_ricci(nxp);
        r = expf(-nxm * nxm - logf(fmaxf(arg, 1e-12f)));
    }
    return 1.0f / (tau_ref + tau / fmaxf(r, 1e-12f));
}

__device__ __forceinline__ float pref_of(int n){
    return (n < N_E) ? (float)n * (179.99f / 1599.0f)
                     : (float)(n - N_E) * (179.99f / 399.0f);
}

// ---------------- weight build (W only; W2 computed on the fly) ----------------
__global__ __launch_bounds__(256) void build_w_kernel(
    const float* __restrict__ jp, const float* __restrict__ pp,
    const float* __restrict__ wp, const float* __restrict__ rnd,
    float* __restrict__ W)
{
    int e = blockIdx.x * 256 + threadIdx.x;     // over 2000*2048
    int i = e >> 11;
    int j = e & (KPAD - 1);
    if (i >= N_NEUR) return;
    if (j >= N_NEUR){ W[e] = 0.0f; return; }
    int isIi = (i >= N_E) ? 1 : 0;
    int isIj = (j >= N_E) ? 1 : 0;
    int conn = 2 * isIj + isIi;
    float J  = expf(jp[conn]);
    float P  = 1.0f / (1.0f + expf(-2.0f * expf(pp[conn])));
    float Wd = expf(wp[conn]);
    float diff = fabsf(pref_of(i) - pref_of(j));
    float dw = DEGF * Wd;
    float z = expf((cosf(TWO_DEG * diff) - 1.0f) / (4.0f * dw * dw));
    float s = 1.0f / (1.0f + expf(-32.0f * (P * z - rnd[i * N_NEUR + j])));
    float sign = isIj ? -1.0f : 1.0f;
    W[e] = sign * J * s;
}

__global__ __launch_bounds__(256) void build_im_kernel(float* __restrict__ IM)
{
    int e = blockIdx.x * 256 + threadIdx.x;     // over 96*2048
    int c = e >> 11;
    int n = e & (KPAD - 1);
    if (n >= N_NEUR){ IM[e] = 0.0f; return; }
    const float contrasts[8] = {0.0f, 0.0432773f, 0.103411f, 0.186966f,
                                0.303066f, 0.464386f, 0.68854f, 1.0f};
    int ci = c / 12;
    int oi = c - ci * 12;
    float orient = (float)oi * 15.0f;
    const float dw = DEGF * 30.0f;
    float g = expf((cosf(TWO_DEG * (orient - pref_of(n))) - 1.0f) / (4.0f * dw * dw));
    IM[e] = contrasts[ci] * 20.0f * g;
}

// ---------------- one Euler step ----------------
// 250 blocks x 1024 threads (16 waves). Block owns neurons [i0, i0+8) x 96 conds.
// Wave w owns chunk-cols [w*4, w*4+4). Lane: ip = lane&1 (i = ip+2m), cq = lane>>1
// (c = cq + 32k). Double-buffered LDS, one barrier per chunk.
__global__ __launch_bounds__(1024, 1) void step_kernel(
    const float* __restrict__ W, const float* __restrict__ IM,
    const float* __restrict__ r_in, float* __restrict__ r_out,
    unsigned int* __restrict__ m_step)
{
    __shared__ float w_lds[2][8 * WSTRIDE];     //  4352 B
    __shared__ float r_lds[2][96 * RSTRIDE];    // 50688 B

    const int t  = threadIdx.x;
    const int wv = t >> 6;          // 0..15
    const int ln = t & 63;
    const int ip = ln & 1;
    const int cq = ln >> 1;         // 0..31
    const int i0 = blockIdx.x * 8;
    const int jb = wv * 4;          // column offset within chunk (floats)

    // staging indices
    const int rrow0 = t >> 4;            // rows 0..63
    const int rcol  = (t & 15) << 2;     // float col within chunk
    const int rrow1 = 64 + (t >> 4);     // rows 64..95 (t < 512)
    const int wrow  = t >> 4;            // t < 128: rows 0..7

    float accv[24];
    #pragma unroll
    for (int q = 0; q < 24; ++q) accv[q] = 0.0f;

    float4 pr0, pr1, pwv;

    // -------- prologue: load + stage chunk 0 --------
    pr0 = *reinterpret_cast<const float4*>(&r_in[rrow0 * KPAD + rcol]);
    if (t < 512) pr1 = *reinterpret_cast<const float4*>(&r_in[rrow1 * KPAD + rcol]);
    if (t < 128) pwv = *reinterpret_cast<const float4*>(&W[(i0 + wrow) * KPAD + rcol]);
    {
        float* p = &r_lds[0][rrow0 * RSTRIDE + rcol];
        *reinterpret_cast<float2*>(p)     = make_float2(pr0.x, pr0.y);
        *reinterpret_cast<float2*>(p + 2) = make_float2(pr0.z, pr0.w);
        if (t < 512){
            float* q = &r_lds[0][rrow1 * RSTRIDE + rcol];
            *reinterpret_cast<float2*>(q)     = make_float2(pr1.x, pr1.y);
            *reinterpret_cast<float2*>(q + 2) = make_float2(pr1.z, pr1.w);
        }
        if (t < 128)
            *reinterpret_cast<float4*>(&w_lds[0][wrow * WSTRIDE + rcol]) = pwv;
    }
    __syncthreads();

    // -------- main K loop: 32 chunks, 1 barrier each --------
    for (int s = 0; s < NCH; ++s){
        const int cur = s & 1, nxt = cur ^ 1;
        if (s + 1 < NCH){
            const int base = (s + 1) * CHUNK;
            pr0 = *reinterpret_cast<const float4*>(&r_in[rrow0 * KPAD + base + rcol]);
            if (t < 512) pr1 = *reinterpret_cast<const float4*>(&r_in[rrow1 * KPAD + base + rcol]);
            if (t < 128) pwv = *reinterpret_cast<const float4*>(&W[(i0 + wrow) * KPAD + base + rcol]);
        }
        const float* wl = w_lds[cur];
        const float* rl = r_lds[cur];
        const float4 w0 = *reinterpret_cast<const float4*>(&wl[(ip    ) * WSTRIDE + jb]);
        const float4 w1 = *reinterpret_cast<const float4*>(&wl[(ip + 2) * WSTRIDE + jb]);
        const float4 w2 = *reinterpret_cast<const float4*>(&wl[(ip + 4) * WSTRIDE + jb]);
        const float4 w3 = *reinterpret_cast<const float4*>(&wl[(ip + 6) * WSTRIDE + jb]);
        float4 u0, u1, u2, u3;
        u0.x = w0.x*w0.x; u0.y = w0.y*w0.y; u0.z = w0.z*w0.z; u0.w = w0.w*w0.w;
        u1.x = w1.x*w1.x; u1.y = w1.y*w1.y; u1.z = w1.z*w1.z; u1.w = w1.w*w1.w;
        u2.x = w2.x*w2.x; u2.y = w2.y*w2.y; u2.z = w2.z*w2.z; u2.w = w2.w*w2.w;
        u3.x = w3.x*w3.x; u3.y = w3.y*w3.y; u3.z = w3.z*w3.z; u3.w = w3.w*w3.w;
        #pragma unroll
        for (int k = 0; k < 3; ++k){
            const float* rp = &rl[(cq + 32 * k) * RSTRIDE + jb];
            const float2 rA = *reinterpret_cast<const float2*>(rp);
            const float2 rB = *reinterpret_cast<const float2*>(rp + 2);
            #define DO_M(m, wv_, uv_)                                                        \
                accv[(m)*3 + k]      = fmaf(rA.x, wv_.x, fmaf(rA.y, wv_.y,                   \
                                       fmaf(rB.x, wv_.z, fmaf(rB.y, wv_.w, accv[(m)*3 + k])))); \
                accv[12 + (m)*3 + k] = fmaf(rA.x, uv_.x, fmaf(rA.y, uv_.y,                   \
                                       fmaf(rB.x, uv_.z, fmaf(rB.y, uv_.w, accv[12 + (m)*3 + k]))));
            DO_M(0, w0, u0)
            DO_M(1, w1, u1)
            DO_M(2, w2, u2)
            DO_M(3, w3, u3)
            #undef DO_M
        }
        if (s + 1 < NCH){
            float* rw = r_lds[nxt];
            float* p = &rw[rrow0 * RSTRIDE + rcol];
            *reinterpret_cast<float2*>(p)     = make_float2(pr0.x, pr0.y);
            *reinterpret_cast<float2*>(p + 2) = make_float2(pr0.z, pr0.w);
            if (t < 512){
                float* q = &rw[rrow1 * RSTRIDE + rcol];
                *reinterpret_cast<float2*>(q)     = make_float2(pr1.x, pr1.y);
                *reinterpret_cast<float2*>(q + 2) = make_float2(pr1.z, pr1.w);
            }
            if (t < 128)
                *reinterpret_cast<float4*>(&w_lds[nxt][wrow * WSTRIDE + rcol]) = pwv;
        }
        __syncthreads();
    }

    // -------- cross-wave reduction tree (16 -> 1), scratch aliases r_lds --------
    float* scratch = &r_lds[0][0];   // 12672 floats >= 8*64*24
    #pragma unroll
    for (int off = 8; off >= 1; off >>= 1){
        if (wv >= off && wv < 2 * off){
            float* dst = scratch + ((wv - off) * 64 + ln) * 24;
            #pragma unroll
            for (int q = 0; q < 24; ++q) dst[q] = accv[q];
        }
        __syncthreads();
        if (wv < off){
            const float* src = scratch + (wv * 64 + ln) * 24;
            #pragma unroll
            for (int q = 0; q < 24; ++q) accv[q] += src[q];
        }
        __syncthreads();
    }

    // -------- epilogue: Phi + update + convergence metric (wave 0 only) --------
    if (wv == 0){
        #pragma unroll
        for (int k = 0; k < 3; ++k){
            const int c = cq + 32 * k;
            float vmax = 0.0f;
            #pragma unroll
            for (int m = 0; m < 4; ++m){
                const int i = i0 + ip + 2 * m;
                const float ms_ = accv[m * 3 + k];
                const float ss_ = accv[12 + m * 3 + k];
                const float mu = fmaf(0.01f, ms_, IM[c * KPAD + i]);
                const float sg = sqrtf(fmaf(0.01f, ss_, 25.0f));
                const bool isI = (i >= N_E);
                const float rate = phi_rate(mu, sg, isI ? 0.001f : 0.005f);
                const float rold = r_in[c * KPAD + i];
                const float dr = (isI ? 0.2f : 0.1f) * (rate - rold);
                const float rnew = rold + dr;
                r_out[c * KPAD + i] = rnew;
                vmax = fmaxf(vmax, fabsf(dr) / fmaxf(fabsf(rnew), 1.0f));
            }
            vmax = fmaxf(vmax, __shfl_xor(vmax, 1));   // merge ip=0/1 (even/odd i)
            if (ip == 0)
                atomicMax(m_step + c, __float_as_uint(vmax * 1e5f));
        }
    }
}

// ---------------- outputs ----------------
__global__ __launch_bounds__(256) void transpose_kernel(
    const float* __restrict__ r_fin, float* __restrict__ out)
{
    int e = blockIdx.x * 256 + threadIdx.x;     // over 192000
    int n = e / NCOND;
    int c = e - n * NCOND;
    out[e] = r_fin[c * KPAD + n];               // out[n*96 + c]
}

__global__ __launch_bounds__(256) void finalize_kernel(
    const unsigned int* __restrict__ m_buf, float* __restrict__ out)
{
    __shared__ float sbuf[256];
    float s = 0.0f;
    for (int idx = threadIdx.x; idx < (NAVG * NCOND); idx += 256)
        s += __uint_as_float(m_buf[(NSTEP - NAVG) * NCOND + idx]);
    sbuf[threadIdx.x] = s;
    __syncthreads();
    for (int st = 128; st > 0; st >>= 1){
        if (threadIdx.x < st) sbuf[threadIdx.x] += sbuf[threadIdx.x + st];
        __syncthreads();
    }
    if (threadIdx.x == 0) out[N_NEUR * NCOND] = sbuf[0] / (float)(NAVG * NCOND);
}

extern "C" void kernel_launch(void* const* d_in, const int* in_sizes, int n_in,
                              void* d_out, int out_size, void* d_ws, size_t ws_size,
                              hipStream_t stream) {
    const float* jp  = (const float*)d_in[0];
    const float* pp  = (const float*)d_in[1];
    const float* wp  = (const float*)d_in[2];
    const float* rnd = (const float*)d_in[3];
    float* out = (float*)d_out;

    float* W  = (float*)d_ws;                          // 2000*2048
    float* IM = W  + (size_t)N_NEUR * KPAD;            // 96*2048
    float* ra = IM + (size_t)NCOND * KPAD;             // 96*2048
    float* rb = ra + (size_t)NCOND * KPAD;             // 96*2048
    float* mb = rb + (size_t)NCOND * KPAD;             // 60*96 uints

    // zero r buffers (pads included; r0 = 0) and the convergence-metric buffer
    hipMemsetAsync(ra, 0, (size_t)(2 * NCOND * KPAD + NSTEP * NCOND) * sizeof(float), stream);

    build_w_kernel<<<(N_NEUR * KPAD) / 256, 256, 0, stream>>>(jp, pp, wp, rnd, W);
    build_im_kernel<<<(NCOND * KPAD) / 256, 256, 0, stream>>>(IM);

    const float* rin = ra;
    float* rout = rb;
    for (int s = 0; s < NSTEP; ++s){
        step_kernel<<<N_NEUR / 8, 1024, 0, stream>>>(W, IM, rin, rout,
                                                     (unsigned int*)mb + s * NCOND);
        float* tmp = (float*)rin; rin = rout; rout = tmp;
    }
    transpose_kernel<<<(N_NEUR * NCOND) / 256, 256, 0, stream>>>(rin, out);
    finalize_kernel<<<1, 256, 0, stream>>>((const unsigned int*)mb, out);
}

// Round 3
// 1433.595 us; speedup vs baseline: 3.2240x; 2.0897x over previous
//
#include <hip/hip_runtime.h>
#include <hip/hip_bf16.h>

#define N_NEUR 2000
#define N_E    1600
#define KPAD   2048
#define NCOND  96
#define NSTEP  60
#define NAVG   15

#define DEGF   0.017453292519943295f
#define TWO_DEG 0.03490658503988659f

typedef __attribute__((ext_vector_type(8))) short bf16x8;
typedef __attribute__((ext_vector_type(4))) float f32x4;

// ---------------- Ricciardi transfer function ----------------
__device__ __forceinline__ float f_ricci(float x){
    float t = -x / (1.0f + x);
    float p = 0.14805913578876898f;
    p = fmaf(p, t, 0.64290613877355551f);
    p = fmaf(p, t, 1.0616084849547165f);
    p = fmaf(p, t, 0.93524391761244940f);
    p = fmaf(p, t, 0.62718906618071668f);
    p = fmaf(p, t, 0.32171431660633076f);
    p = fmaf(p, t, 0.32056016125642045f);
    p = fmaf(p, t, 0.77373949685442023f);
    p = fmaf(p, t, 0.22757881388024176f);
    return logf(2.0f * x + 1.0f) + p * t;
}

__device__ __forceinline__ float g_ricci(float x){
    float z = x / (2.0f + x);
    float z2 = z * z, z3 = z2 * z, z4 = z2 * z2, z5 = z4 * z, z6 = z3 * z3, z7 = z6 * z, z8 = z4 * z4;
    float en = 3.5441754117462949f * z - 7.0529131065835378f * z2 - 56.532378057580381f * z3
             + 279.56761105465944f * z4 - 520.37554793489681f * z5
             + 456.58245777026514f * z6 - 155.73340457809226f * z7;
    float de = 1.0f - 4.1357968834226053f * z - 7.2984226138266743f * z2
             + 98.656602235468327f * z3 - 334.20436223415163f * z4
             + 601.08633903294185f * z5 - 599.58577549598340f * z6
             + 277.18420330693891f * z7 - 16.445022798669722f * z8;
    return en / de;
}

__device__ __forceinline__ float phi_rate(float mu, float sigma, float tau_ref){
    const float tau = 0.01f;
    float xp = mu / sigma;
    float xm = (mu - 20.0f) / sigma;
    float r;
    if (xm > 0.0f){
        r = 1.0f / (f_ricci(xp) - f_ricci(xm));
    } else if (xp > 0.0f){
        float nxm = fminf(-xm, 9.0f);
        r = 1.0f / (f_ricci(xp) + expf(nxm * nxm) * g_ricci(nxm));
    } else {
        float nxp = fminf(fmaxf(-xp, 0.0f), 9.0f);
        float nxm = fminf(-xm, 9.0f);
        float arg = g_ricci(nxm) - expf(nxp * nxp - nxm * nxm) * g_ricci(nxp);
        r = expf(-nxm * nxm - logf(fmaxf(arg, 1e-12f)));
    }
    return 1.0f / (tau_ref + tau / fmaxf(r, 1e-12f));
}

__device__ __forceinline__ float pref_of(int n){
    return (n < N_E) ? (float)n * (179.99f / 1599.0f)
                     : (float)(n - N_E) * (179.99f / 399.0f);
}

__device__ __forceinline__ unsigned short bf16_rne(float f){
    unsigned int u = __float_as_uint(f);
    u = (u + 0x7fffu + ((u >> 16) & 1u)) >> 16;
    return (unsigned short)u;
}

// ---------------- weight build: Wh, Wl (split), W2h, padded to 2048x2048 ----------------
__global__ __launch_bounds__(256) void build_w_kernel(
    const float* __restrict__ jp, const float* __restrict__ pp,
    const float* __restrict__ wp, const float* __restrict__ rnd,
    unsigned short* __restrict__ Wh, unsigned short* __restrict__ Wl,
    unsigned short* __restrict__ W2h)
{
    int e = blockIdx.x * 256 + threadIdx.x;     // over 2048*2048
    int i = e >> 11;
    int j = e & (KPAD - 1);
    float w = 0.0f;
    if (i < N_NEUR && j < N_NEUR){
        int isIi = (i >= N_E) ? 1 : 0;
        int isIj = (j >= N_E) ? 1 : 0;
        int conn = 2 * isIj + isIi;
        float J  = expf(jp[conn]);
        float P  = 1.0f / (1.0f + expf(-2.0f * expf(pp[conn])));
        float Wd = expf(wp[conn]);
        float diff = fabsf(pref_of(i) - pref_of(j));
        float dw = DEGF * Wd;
        float z = expf((cosf(TWO_DEG * diff) - 1.0f) / (4.0f * dw * dw));
        float s = 1.0f / (1.0f + expf(-32.0f * (P * z - rnd[i * N_NEUR + j])));
        float sign = isIj ? -1.0f : 1.0f;
        w = sign * J * s;
    }
    unsigned short hb = bf16_rne(w);
    float hf = __uint_as_float(((unsigned int)hb) << 16);
    Wh[e] = hb;
    Wl[e] = bf16_rne(w - hf);
    W2h[e] = bf16_rne(w * w);
}

__global__ __launch_bounds__(256) void build_im_kernel(float* __restrict__ IM)
{
    int e = blockIdx.x * 256 + threadIdx.x;     // over 96*2048
    int c = e >> 11;
    int n = e & (KPAD - 1);
    if (n >= N_NEUR){ IM[e] = 0.0f; return; }
    const float contrasts[8] = {0.0f, 0.0432773f, 0.103411f, 0.186966f,
                                0.303066f, 0.464386f, 0.68854f, 1.0f};
    int ci = c / 12;
    int oi = c - ci * 12;
    float orient = (float)oi * 15.0f;
    const float dw = DEGF * 30.0f;
    float g = expf((cosf(TWO_DEG * (orient - pref_of(n))) - 1.0f) / (4.0f * dw * dw));
    IM[e] = contrasts[ci] * 20.0f * g;
}

// ---------------- one Euler step (MFMA) ----------------
// grid 250 = (125 neuron-tiles x 2 cond-halves), 512 threads = 8 waves.
// Block output: 48 conds x 16 neurons. Wave w owns K-slice [w*256, w*256+256).
// mu  <- rh*Wh + rh*Wl + rl*Wh   (split-bf16 ~ fp32 precision)
// sg2 <- rh*W2h + rl*W2h
__global__ __launch_bounds__(512, 2) void step_kernel(
    const unsigned short* __restrict__ Wh, const unsigned short* __restrict__ Wl,
    const unsigned short* __restrict__ W2h,
    const unsigned short* __restrict__ rh_in, const unsigned short* __restrict__ rl_in,
    unsigned short* __restrict__ rh_out, unsigned short* __restrict__ rl_out,
    const float* __restrict__ IM, float* __restrict__ rf,
    unsigned int* __restrict__ m_step)
{
    __shared__ float red[8][64][24];    // 48 KiB partial-acc scratch
    __shared__ float vbuf[48][16];

    const int t  = threadIdx.x;
    const int wv = t >> 6;
    const int ln = t & 63;
    const int tile  = blockIdx.x >> 1;          // 0..124
    const int half  = blockIdx.x & 1;           // 0..1
    const int nbase = tile * 16;
    const int cbase = half * 48;

    const int lrow = ln & 15;                   // A-row (cond) / B-col (neuron) in frag
    const int lk8  = (ln >> 4) * 8;             // k sub-offset

    f32x4 accm[3], accs[3];
    #pragma unroll
    for (int m = 0; m < 3; ++m){
        accm[m] = (f32x4){0.0f, 0.0f, 0.0f, 0.0f};
        accs[m] = (f32x4){0.0f, 0.0f, 0.0f, 0.0f};
    }

    const int nrow = nbase + lrow;              // W row for B-frags
    const unsigned short* pwh = &Wh [nrow * KPAD + lk8];
    const unsigned short* pwl = &Wl [nrow * KPAD + lk8];
    const unsigned short* pw2 = &W2h[nrow * KPAD + lk8];
    const unsigned short* pah0 = &rh_in[(cbase +  0 + lrow) * KPAD + lk8];
    const unsigned short* pah1 = &rh_in[(cbase + 16 + lrow) * KPAD + lk8];
    const unsigned short* pah2 = &rh_in[(cbase + 32 + lrow) * KPAD + lk8];
    const unsigned short* pal0 = &rl_in[(cbase +  0 + lrow) * KPAD + lk8];
    const unsigned short* pal1 = &rl_in[(cbase + 16 + lrow) * KPAD + lk8];
    const unsigned short* pal2 = &rl_in[(cbase + 32 + lrow) * KPAD + lk8];

    #pragma unroll 2
    for (int s = 0; s < 8; ++s){
        const int k = (wv * 8 + s) * 32;        // K-step base
        const bf16x8 bwh = *reinterpret_cast<const bf16x8*>(pwh + k);
        const bf16x8 bwl = *reinterpret_cast<const bf16x8*>(pwl + k);
        const bf16x8 bw2 = *reinterpret_cast<const bf16x8*>(pw2 + k);
        const bf16x8 ah0 = *reinterpret_cast<const bf16x8*>(pah0 + k);
        const bf16x8 ah1 = *reinterpret_cast<const bf16x8*>(pah1 + k);
        const bf16x8 ah2 = *reinterpret_cast<const bf16x8*>(pah2 + k);
        const bf16x8 al0 = *reinterpret_cast<const bf16x8*>(pal0 + k);
        const bf16x8 al1 = *reinterpret_cast<const bf16x8*>(pal1 + k);
        const bf16x8 al2 = *reinterpret_cast<const bf16x8*>(pal2 + k);
        accm[0] = __builtin_amdgcn_mfma_f32_16x16x32_bf16(ah0, bwh, accm[0], 0, 0, 0);
        accm[0] = __builtin_amdgcn_mfma_f32_16x16x32_bf16(ah0, bwl, accm[0], 0, 0, 0);
        accm[0] = __builtin_amdgcn_mfma_f32_16x16x32_bf16(al0, bwh, accm[0], 0, 0, 0);
        accs[0] = __builtin_amdgcn_mfma_f32_16x16x32_bf16(ah0, bw2, accs[0], 0, 0, 0);
        accs[0] = __builtin_amdgcn_mfma_f32_16x16x32_bf16(al0, bw2, accs[0], 0, 0, 0);
        accm[1] = __builtin_amdgcn_mfma_f32_16x16x32_bf16(ah1, bwh, accm[1], 0, 0, 0);
        accm[1] = __builtin_amdgcn_mfma_f32_16x16x32_bf16(ah1, bwl, accm[1], 0, 0, 0);
        accm[1] = __builtin_amdgcn_mfma_f32_16x16x32_bf16(al1, bwh, accm[1], 0, 0, 0);
        accs[1] = __builtin_amdgcn_mfma_f32_16x16x32_bf16(ah1, bw2, accs[1], 0, 0, 0);
        accs[1] = __builtin_amdgcn_mfma_f32_16x16x32_bf16(al1, bw2, accs[1], 0, 0, 0);
        accm[2] = __builtin_amdgcn_mfma_f32_16x16x32_bf16(ah2, bwh, accm[2], 0, 0, 0);
        accm[2] = __builtin_amdgcn_mfma_f32_16x16x32_bf16(ah2, bwl, accm[2], 0, 0, 0);
        accm[2] = __builtin_amdgcn_mfma_f32_16x16x32_bf16(al2, bwh, accm[2], 0, 0, 0);
        accs[2] = __builtin_amdgcn_mfma_f32_16x16x32_bf16(ah2, bw2, accs[2], 0, 0, 0);
        accs[2] = __builtin_amdgcn_mfma_f32_16x16x32_bf16(al2, bw2, accs[2], 0, 0, 0);
    }

    // -------- cross-wave K-reduction --------
    #pragma unroll
    for (int m = 0; m < 3; ++m)
        #pragma unroll
        for (int q = 0; q < 4; ++q){
            red[wv][ln][m * 4 + q]      = accm[m][q];
            red[wv][ln][12 + m * 4 + q] = accs[m][q];
        }
    __syncthreads();

    // -------- epilogue: Phi + update + r split + metric --------
    for (int o = t; o < 768; o += 512){
        const int c_local = o >> 4;             // 0..47
        const int n_local = o & 15;
        const int m  = c_local >> 4;
        const int rr = c_local & 15;
        const int q  = rr & 3;
        const int lane = (rr >> 2) * 16 + n_local;
        float ms = 0.0f, ss = 0.0f;
        #pragma unroll
        for (int w = 0; w < 8; ++w){
            ms += red[w][lane][m * 4 + q];
            ss += red[w][lane][12 + m * 4 + q];
        }
        const int c = cbase + c_local;
        const int i = nbase + n_local;
        const float mu = fmaf(0.01f, ms, IM[c * KPAD + i]);
        const float sg = sqrtf(fmaf(0.01f, ss, 25.0f));
        const bool isI = (i >= N_E);
        const float rate = phi_rate(mu, sg, isI ? 0.001f : 0.005f);
        const float rold = rf[c * KPAD + i];
        const float dr = (isI ? 0.2f : 0.1f) * (rate - rold);
        const float rnew = rold + dr;
        rf[c * KPAD + i] = rnew;
        const unsigned short hb = bf16_rne(rnew);
        const float hf = __uint_as_float(((unsigned int)hb) << 16);
        rh_out[c * KPAD + i] = hb;
        rl_out[c * KPAD + i] = bf16_rne(rnew - hf);
        vbuf[c_local][n_local] = fabsf(dr) / fmaxf(fabsf(rnew), 1.0f);
    }
    __syncthreads();
    if (t < 48){
        float mx = 0.0f;
        #pragma unroll
        for (int j = 0; j < 16; ++j) mx = fmaxf(mx, vbuf[t][j]);
        atomicMax(m_step + cbase + t, __float_as_uint(mx * 1e5f));
    }
}

// ---------------- outputs ----------------
__global__ __launch_bounds__(256) void transpose_kernel(
    const float* __restrict__ r_fin, float* __restrict__ out)
{
    int e = blockIdx.x * 256 + threadIdx.x;     // over 192000
    int n = e / NCOND;
    int c = e - n * NCOND;
    out[e] = r_fin[c * KPAD + n];               // out[n*96 + c]
}

__global__ __launch_bounds__(256) void finalize_kernel(
    const unsigned int* __restrict__ m_buf, float* __restrict__ out)
{
    __shared__ float sbuf[256];
    float s = 0.0f;
    for (int idx = threadIdx.x; idx < (NAVG * NCOND); idx += 256)
        s += __uint_as_float(m_buf[(NSTEP - NAVG) * NCOND + idx]);
    sbuf[threadIdx.x] = s;
    __syncthreads();
    for (int st = 128; st > 0; st >>= 1){
        if (threadIdx.x < st) sbuf[threadIdx.x] += sbuf[threadIdx.x + st];
        __syncthreads();
    }
    if (threadIdx.x == 0) out[N_NEUR * NCOND] = sbuf[0] / (float)(NAVG * NCOND);
}

extern "C" void kernel_launch(void* const* d_in, const int* in_sizes, int n_in,
                              void* d_out, int out_size, void* d_ws, size_t ws_size,
                              hipStream_t stream) {
    const float* jp  = (const float*)d_in[0];
    const float* pp  = (const float*)d_in[1];
    const float* wp  = (const float*)d_in[2];
    const float* rnd = (const float*)d_in[3];
    float* out = (float*)d_out;

    const size_t WELEMS = (size_t)KPAD * KPAD;          // 4,194,304
    const size_t RELEMS = (size_t)NCOND * KPAD;         // 196,608
    unsigned short* Wh  = (unsigned short*)d_ws;
    unsigned short* Wl  = Wh  + WELEMS;
    unsigned short* W2h = Wl  + WELEMS;
    unsigned short* rhA = W2h + WELEMS;
    unsigned short* rlA = rhA + RELEMS;
    unsigned short* rhB = rlA + RELEMS;
    unsigned short* rlB = rhB + RELEMS;
    float* rf = (float*)(rlB + RELEMS);
    float* IM = rf + RELEMS;
    unsigned int* mb = (unsigned int*)(IM + RELEMS);    // 60*96

    // zero: rhA,rlA,rhB,rlB (bf16) + rf (f32) — contiguous; and the metric buffer
    hipMemsetAsync(rhA, 0, 4 * RELEMS * sizeof(unsigned short) + RELEMS * sizeof(float), stream);
    hipMemsetAsync(mb, 0, (size_t)NSTEP * NCOND * sizeof(unsigned int), stream);

    build_w_kernel<<<(int)(WELEMS / 256), 256, 0, stream>>>(jp, pp, wp, rnd, Wh, Wl, W2h);
    build_im_kernel<<<(int)(RELEMS / 256), 256, 0, stream>>>(IM);

    const unsigned short* rh_in = rhA;
    const unsigned short* rl_in = rlA;
    unsigned short* rh_out = rhB;
    unsigned short* rl_out = rlB;
    for (int s = 0; s < NSTEP; ++s){
        step_kernel<<<250, 512, 0, stream>>>(Wh, Wl, W2h, rh_in, rl_in,
                                             rh_out, rl_out, IM, rf, mb + s * NCOND);
        const unsigned short* th = rh_in; rh_in = rh_out; rh_out = (unsigned short*)th;
        const unsigned short* tl = rl_in; rl_in = rl_out; rl_out = (unsigned short*)tl;
    }
    transpose_kernel<<<(N_NEUR * NCOND) / 256, 256, 0, stream>>>(rf, out);
    finalize_kernel<<<1, 256, 0, stream>>>(mb, out);
}

// Round 4
// 1326.741 us; speedup vs baseline: 3.4836x; 1.0805x over previous
//
#include <hip/hip_runtime.h>
#include <hip/hip_bf16.h>

#define N_NEUR 2000
#define N_E    1600
#define KPAD   2048
#define NCOND  96
#define NSTEP  60
#define NAVG   15

#define DEGF   0.017453292519943295f
#define TWO_DEG 0.03490658503988659f

typedef __attribute__((ext_vector_type(8))) short bf16x8;
typedef __attribute__((ext_vector_type(4))) float f32x4;

// ---------------- Ricciardi transfer function ----------------
__device__ __forceinline__ float f_ricci(float x){
    float t = -x / (1.0f + x);
    float p = 0.14805913578876898f;
    p = fmaf(p, t, 0.64290613877355551f);
    p = fmaf(p, t, 1.0616084849547165f);
    p = fmaf(p, t, 0.93524391761244940f);
    p = fmaf(p, t, 0.62718906618071668f);
    p = fmaf(p, t, 0.32171431660633076f);
    p = fmaf(p, t, 0.32056016125642045f);
    p = fmaf(p, t, 0.77373949685442023f);
    p = fmaf(p, t, 0.22757881388024176f);
    return logf(2.0f * x + 1.0f) + p * t;
}

__device__ __forceinline__ float g_ricci(float x){
    float z = x / (2.0f + x);
    float z2 = z * z, z3 = z2 * z, z4 = z2 * z2, z5 = z4 * z, z6 = z3 * z3, z7 = z6 * z, z8 = z4 * z4;
    float en = 3.5441754117462949f * z - 7.0529131065835378f * z2 - 56.532378057580381f * z3
             + 279.56761105465944f * z4 - 520.37554793489681f * z5
             + 456.58245777026514f * z6 - 155.73340457809226f * z7;
    float de = 1.0f - 4.1357968834226053f * z - 7.2984226138266743f * z2
             + 98.656602235468327f * z3 - 334.20436223415163f * z4
             + 601.08633903294185f * z5 - 599.58577549598340f * z6
             + 277.18420330693891f * z7 - 16.445022798669722f * z8;
    return en / de;
}

__device__ __forceinline__ float phi_rate(float mu, float sigma, float tau_ref){
    const float tau = 0.01f;
    float xp = mu / sigma;
    float xm = (mu - 20.0f) / sigma;
    float r;
    if (xm > 0.0f){
        r = 1.0f / (f_ricci(xp) - f_ricci(xm));
    } else if (xp > 0.0f){
        float nxm = fminf(-xm, 9.0f);
        r = 1.0f / (f_ricci(xp) + expf(nxm * nxm) * g_ricci(nxm));
    } else {
        float nxp = fminf(fmaxf(-xp, 0.0f), 9.0f);
        float nxm = fminf(-xm, 9.0f);
        float arg = g_ricci(nxm) - expf(nxp * nxp - nxm * nxm) * g_ricci(nxp);
        r = expf(-nxm * nxm - logf(fmaxf(arg, 1e-12f)));
    }
    return 1.0f / (tau_ref + tau / fmaxf(r, 1e-12f));
}

__device__ __forceinline__ float pref_of(int n){
    return (n < N_E) ? (float)n * (179.99f / 1599.0f)
                     : (float)(n - N_E) * (179.99f / 399.0f);
}

__device__ __forceinline__ unsigned short bf16_rne(float f){
    unsigned int u = __float_as_uint(f);
    u = (u + 0x7fffu + ((u >> 16) & 1u)) >> 16;
    return (unsigned short)u;
}

// ---------------- weight build: Wh, Wl (split), W2h, padded to 2048x2048 ----------------
__global__ __launch_bounds__(256) void build_w_kernel(
    const float* __restrict__ jp, const float* __restrict__ pp,
    const float* __restrict__ wp, const float* __restrict__ rnd,
    unsigned short* __restrict__ Wh, unsigned short* __restrict__ Wl,
    unsigned short* __restrict__ W2h)
{
    int e = blockIdx.x * 256 + threadIdx.x;     // over 2048*2048
    int i = e >> 11;
    int j = e & (KPAD - 1);
    float w = 0.0f;
    if (i < N_NEUR && j < N_NEUR){
        int isIi = (i >= N_E) ? 1 : 0;
        int isIj = (j >= N_E) ? 1 : 0;
        int conn = 2 * isIj + isIi;
        float J  = expf(jp[conn]);
        float P  = 1.0f / (1.0f + expf(-2.0f * expf(pp[conn])));
        float Wd = expf(wp[conn]);
        float diff = fabsf(pref_of(i) - pref_of(j));
        float dw = DEGF * Wd;
        float z = expf((cosf(TWO_DEG * diff) - 1.0f) / (4.0f * dw * dw));
        float s = 1.0f / (1.0f + expf(-32.0f * (P * z - rnd[i * N_NEUR + j])));
        float sign = isIj ? -1.0f : 1.0f;
        w = sign * J * s;
    }
    unsigned short hb = bf16_rne(w);
    float hf = __uint_as_float(((unsigned int)hb) << 16);
    Wh[e] = hb;
    Wl[e] = bf16_rne(w - hf);
    W2h[e] = bf16_rne(w * w);
}

__global__ __launch_bounds__(256) void build_im_kernel(float* __restrict__ IM)
{
    int e = blockIdx.x * 256 + threadIdx.x;     // over 96*2048
    int c = e >> 11;
    int n = e & (KPAD - 1);
    if (n >= N_NEUR){ IM[e] = 0.0f; return; }
    const float contrasts[8] = {0.0f, 0.0432773f, 0.103411f, 0.186966f,
                                0.303066f, 0.464386f, 0.68854f, 1.0f};
    int ci = c / 12;
    int oi = c - ci * 12;
    float orient = (float)oi * 15.0f;
    const float dw = DEGF * 30.0f;
    float g = expf((cosf(TWO_DEG * (orient - pref_of(n))) - 1.0f) / (4.0f * dw * dw));
    IM[e] = contrasts[ci] * 20.0f * g;
}

// ---------------- one Euler step (MFMA) ----------------
// grid 256 (6 idle), XCD-swizzled: xcd=bid&7, slot=bid>>3, v=xcd*32+slot,
// tile=v>>1 (16 neurons), half=v&1 (48 conds). 512 threads = 8 waves; wave w
// owns K-slice [w*256, w*256+256). Depth-3 register pipeline on the 9 frags.
// mu  <- rh*Wh + rh*Wl + rl*Wh   (split-bf16 ~ fp32 precision)
// sg2 <- rh*W2h + rl*W2h
__global__ __launch_bounds__(512, 2) void step_kernel(
    const unsigned short* __restrict__ Wh, const unsigned short* __restrict__ Wl,
    const unsigned short* __restrict__ W2h,
    const unsigned short* __restrict__ rh_in, const unsigned short* __restrict__ rl_in,
    unsigned short* __restrict__ rh_out, unsigned short* __restrict__ rl_out,
    const float* __restrict__ IM, float* __restrict__ rf,
    unsigned int* __restrict__ m_step)
{
    __shared__ float red[8][64][25];    // padded stride 25: conflict-free
    __shared__ float vbuf[48][16];

    const int bid  = blockIdx.x;
    const int xcd  = bid & 7;
    const int slot = bid >> 3;
    const int v    = xcd * 32 + slot;
    const int tile = v >> 1;
    const int half = v & 1;
    if (tile >= 125) return;

    const int t  = threadIdx.x;
    const int wv = t >> 6;
    const int ln = t & 63;
    const int nbase = tile * 16;
    const int cbase = half * 48;

    const int lrow = ln & 15;                   // A-row (cond) / B-col (neuron) in frag
    const int lk8  = (ln >> 4) * 8;             // k sub-offset

    f32x4 accm[3], accs[3];
    #pragma unroll
    for (int m = 0; m < 3; ++m){
        accm[m] = (f32x4){0.0f, 0.0f, 0.0f, 0.0f};
        accs[m] = (f32x4){0.0f, 0.0f, 0.0f, 0.0f};
    }

    const int kw = wv * 256 + lk8;              // wave's K-slice base + lane sub-k
    const int nrow = nbase + lrow;
    const unsigned short* pwh  = &Wh [nrow * KPAD + kw];
    const unsigned short* pwl  = &Wl [nrow * KPAD + kw];
    const unsigned short* pw2  = &W2h[nrow * KPAD + kw];
    const unsigned short* pah0 = &rh_in[(cbase +  0 + lrow) * KPAD + kw];
    const unsigned short* pah1 = &rh_in[(cbase + 16 + lrow) * KPAD + kw];
    const unsigned short* pah2 = &rh_in[(cbase + 32 + lrow) * KPAD + kw];
    const unsigned short* pal0 = &rl_in[(cbase +  0 + lrow) * KPAD + kw];
    const unsigned short* pal1 = &rl_in[(cbase + 16 + lrow) * KPAD + kw];
    const unsigned short* pal2 = &rl_in[(cbase + 32 + lrow) * KPAD + kw];

    // depth-3 register pipeline; all indices static after full unroll
    bf16x8 f[3][9];
    #define LOADF(buf, s) do {                                                  \
        const int kk = (s) * 32;                                                \
        f[buf][0] = *reinterpret_cast<const bf16x8*>(pwh  + kk);                \
        f[buf][1] = *reinterpret_cast<const bf16x8*>(pwl  + kk);                \
        f[buf][2] = *reinterpret_cast<const bf16x8*>(pw2  + kk);                \
        f[buf][3] = *reinterpret_cast<const bf16x8*>(pah0 + kk);                \
        f[buf][4] = *reinterpret_cast<const bf16x8*>(pah1 + kk);                \
        f[buf][5] = *reinterpret_cast<const bf16x8*>(pah2 + kk);                \
        f[buf][6] = *reinterpret_cast<const bf16x8*>(pal0 + kk);                \
        f[buf][7] = *reinterpret_cast<const bf16x8*>(pal1 + kk);                \
        f[buf][8] = *reinterpret_cast<const bf16x8*>(pal2 + kk);                \
    } while (0)

    LOADF(0, 0);
    LOADF(1, 1);
    #pragma unroll
    for (int s = 0; s < 8; ++s){
        const int cur = s % 3;
        if (s + 2 < 8){ const int nx = (s + 2) % 3; LOADF(nx, s + 2); }
        const bf16x8 bwh = f[cur][0], bwl = f[cur][1], bw2 = f[cur][2];
        accm[0] = __builtin_amdgcn_mfma_f32_16x16x32_bf16(f[cur][3], bwh, accm[0], 0, 0, 0);
        accm[0] = __builtin_amdgcn_mfma_f32_16x16x32_bf16(f[cur][3], bwl, accm[0], 0, 0, 0);
        accm[0] = __builtin_amdgcn_mfma_f32_16x16x32_bf16(f[cur][6], bwh, accm[0], 0, 0, 0);
        accs[0] = __builtin_amdgcn_mfma_f32_16x16x32_bf16(f[cur][3], bw2, accs[0], 0, 0, 0);
        accs[0] = __builtin_amdgcn_mfma_f32_16x16x32_bf16(f[cur][6], bw2, accs[0], 0, 0, 0);
        accm[1] = __builtin_amdgcn_mfma_f32_16x16x32_bf16(f[cur][4], bwh, accm[1], 0, 0, 0);
        accm[1] = __builtin_amdgcn_mfma_f32_16x16x32_bf16(f[cur][4], bwl, accm[1], 0, 0, 0);
        accm[1] = __builtin_amdgcn_mfma_f32_16x16x32_bf16(f[cur][7], bwh, accm[1], 0, 0, 0);
        accs[1] = __builtin_amdgcn_mfma_f32_16x16x32_bf16(f[cur][4], bw2, accs[1], 0, 0, 0);
        accs[1] = __builtin_amdgcn_mfma_f32_16x16x32_bf16(f[cur][7], bw2, accs[1], 0, 0, 0);
        accm[2] = __builtin_amdgcn_mfma_f32_16x16x32_bf16(f[cur][5], bwh, accm[2], 0, 0, 0);
        accm[2] = __builtin_amdgcn_mfma_f32_16x16x32_bf16(f[cur][5], bwl, accm[2], 0, 0, 0);
        accm[2] = __builtin_amdgcn_mfma_f32_16x16x32_bf16(f[cur][8], bwh, accm[2], 0, 0, 0);
        accs[2] = __builtin_amdgcn_mfma_f32_16x16x32_bf16(f[cur][5], bw2, accs[2], 0, 0, 0);
        accs[2] = __builtin_amdgcn_mfma_f32_16x16x32_bf16(f[cur][8], bw2, accs[2], 0, 0, 0);
    }
    #undef LOADF

    // -------- cross-wave K-reduction --------
    #pragma unroll
    for (int m = 0; m < 3; ++m)
        #pragma unroll
        for (int q = 0; q < 4; ++q){
            red[wv][ln][m * 4 + q]      = accm[m][q];
            red[wv][ln][12 + m * 4 + q] = accs[m][q];
        }
    __syncthreads();

    // -------- epilogue: Phi + update + r split + metric --------
    for (int o = t; o < 768; o += 512){
        const int c_local = o >> 4;             // 0..47
        const int n_local = o & 15;
        const int m  = c_local >> 4;
        const int rr = c_local & 15;
        const int q  = rr & 3;
        const int lane = (rr >> 2) * 16 + n_local;
        float ms = 0.0f, ss = 0.0f;
        #pragma unroll
        for (int w = 0; w < 8; ++w){
            ms += red[w][lane][m * 4 + q];
            ss += red[w][lane][12 + m * 4 + q];
        }
        const int c = cbase + c_local;
        const int i = nbase + n_local;
        const float mu = fmaf(0.01f, ms, IM[c * KPAD + i]);
        const float sg = sqrtf(fmaf(0.01f, ss, 25.0f));
        const bool isI = (i >= N_E);
        const float rate = phi_rate(mu, sg, isI ? 0.001f : 0.005f);
        const float rold = rf[c * KPAD + i];
        const float dr = (isI ? 0.2f : 0.1f) * (rate - rold);
        const float rnew = rold + dr;
        rf[c * KPAD + i] = rnew;
        const unsigned short hb = bf16_rne(rnew);
        const float hf = __uint_as_float(((unsigned int)hb) << 16);
        rh_out[c * KPAD + i] = hb;
        rl_out[c * KPAD + i] = bf16_rne(rnew - hf);
        vbuf[c_local][n_local] = fabsf(dr) / fmaxf(fabsf(rnew), 1.0f);
    }
    __syncthreads();
    if (t < 48){
        float mx = 0.0f;
        #pragma unroll
        for (int j = 0; j < 16; ++j) mx = fmaxf(mx, vbuf[t][j]);
        atomicMax(m_step + cbase + t, __float_as_uint(mx * 1e5f));
    }
}

// ---------------- outputs ----------------
__global__ __launch_bounds__(256) void transpose_kernel(
    const float* __restrict__ r_fin, float* __restrict__ out)
{
    int e = blockIdx.x * 256 + threadIdx.x;     // over 192000
    int n = e / NCOND;
    int c = e - n * NCOND;
    out[e] = r_fin[c * KPAD + n];               // out[n*96 + c]
}

__global__ __launch_bounds__(256) void finalize_kernel(
    const unsigned int* __restrict__ m_buf, float* __restrict__ out)
{
    __shared__ float sbuf[256];
    float s = 0.0f;
    for (int idx = threadIdx.x; idx < (NAVG * NCOND); idx += 256)
        s += __uint_as_float(m_buf[(NSTEP - NAVG) * NCOND + idx]);
    sbuf[threadIdx.x] = s;
    __syncthreads();
    for (int st = 128; st > 0; st >>= 1){
        if (threadIdx.x < st) sbuf[threadIdx.x] += sbuf[threadIdx.x + st];
        __syncthreads();
    }
    if (threadIdx.x == 0) out[N_NEUR * NCOND] = sbuf[0] / (float)(NAVG * NCOND);
}

extern "C" void kernel_launch(void* const* d_in, const int* in_sizes, int n_in,
                              void* d_out, int out_size, void* d_ws, size_t ws_size,
                              hipStream_t stream) {
    const float* jp  = (const float*)d_in[0];
    const float* pp  = (const float*)d_in[1];
    const float* wp  = (const float*)d_in[2];
    const float* rnd = (const float*)d_in[3];
    float* out = (float*)d_out;

    const size_t WELEMS = (size_t)KPAD * KPAD;          // 4,194,304
    const size_t RELEMS = (size_t)NCOND * KPAD;         // 196,608
    unsigned short* Wh  = (unsigned short*)d_ws;
    unsigned short* Wl  = Wh  + WELEMS;
    unsigned short* W2h = Wl  + WELEMS;
    unsigned short* rhA = W2h + WELEMS;
    unsigned short* rlA = rhA + RELEMS;
    unsigned short* rhB = rlA + RELEMS;
    unsigned short* rlB = rhB + RELEMS;
    float* rf = (float*)(rlB + RELEMS);
    float* IM = rf + RELEMS;
    unsigned int* mb = (unsigned int*)(IM + RELEMS);    // 60*96

    // zero: rhA,rlA,rhB,rlB (bf16) + rf (f32) — contiguous; and the metric buffer
    hipMemsetAsync(rhA, 0, 4 * RELEMS * sizeof(unsigned short) + RELEMS * sizeof(float), stream);
    hipMemsetAsync(mb, 0, (size_t)NSTEP * NCOND * sizeof(unsigned int), stream);

    build_w_kernel<<<(int)(WELEMS / 256), 256, 0, stream>>>(jp, pp, wp, rnd, Wh, Wl, W2h);
    build_im_kernel<<<(int)(RELEMS / 256), 256, 0, stream>>>(IM);

    const unsigned short* rh_in = rhA;
    const unsigned short* rl_in = rlA;
    unsigned short* rh_out = rhB;
    unsigned short* rl_out = rlB;
    for (int s = 0; s < NSTEP; ++s){
        step_kernel<<<256, 512, 0, stream>>>(Wh, Wl, W2h, rh_in, rl_in,
                                             rh_out, rl_out, IM, rf, mb + s * NCOND);
        const unsigned short* th = rh_in; rh_in = rh_out; rh_out = (unsigned short*)th;
        const unsigned short* tl = rl_in; rl_in = rl_out; rl_out = (unsigned short*)tl;
    }
    transpose_kernel<<<(N_NEUR * NCOND) / 256, 256, 0, stream>>>(rf, out);
    finalize_kernel<<<1, 256, 0, stream>>>(mb, out);
}